// Round 1
// baseline (79.823 us; speedup 1.0000x reference)
//
#include <hip/hip_runtime.h>
#include <math.h>

#define EPSV 1e-5f

constexpr int BLOCK = 256;
constexpr int EPT   = 4;             // elements per thread
constexpr int ELEMS = BLOCK * EPT;   // 1024 elements per block

__global__ __launch_bounds__(BLOCK) void lie_se2_kernel(
    const float* __restrict__ in,   // [n,3]
    float* __restrict__ out,        // [n,3,3]
    long long n)
{
    __shared__ float lds[ELEMS * 9];   // 36 KB; reused: in-stage (12KB) then out-stage (36KB)
    const int t = threadIdx.x;
    const long long base = (long long)blockIdx.x * ELEMS;

    if (base + ELEMS <= n) {
        // ---------- fast path: full tile ----------
        // stage input: 3*ELEMS floats = 768 float4, coalesced
        const float4* in4 = (const float4*)(in + base * 3);
        float4* lds4 = (float4*)lds;
        #pragma unroll
        for (int k = 0; k < 3; ++k)
            lds4[t + k * BLOCK] = in4[t + k * BLOCK];
        __syncthreads();

        // per-element inputs -> registers
        float ux[EPT], uy[EPT], wz[EPT];
        #pragma unroll
        for (int j = 0; j < EPT; ++j) {
            int e = t + j * BLOCK;
            ux[j] = lds[3 * e + 0];
            uy[j] = lds[3 * e + 1];
            wz[j] = lds[3 * e + 2];
        }
        __syncthreads();

        // compute, write 9 outputs per element to LDS
        #pragma unroll
        for (int j = 0; j < EPT; ++j) {
            int e = t + j * BLOCK;
            float w   = wz[j];
            float th2 = w * w;
            float th  = fabsf(w);                 // sqrt(w*w)
            float s, c;
            sincosf(th, &s, &c);
            float A   = s / (th + EPSV);
            float Bc  = (1.0f - c) / (th2 + EPSV);
            float Cc  = (1.0f - A) / (th2 + EPSV);
            float r00 = 1.0f - Bc * th2;
            float Aw  = A * w;
            float v00 = 1.0f - Cc * th2;
            float Bw  = Bc * w;
            float tx  = v00 * ux[j] - Bw * uy[j];
            float ty  = Bw * ux[j] + v00 * uy[j];
            float* o = lds + 9 * e;
            o[0] = r00;  o[1] = -Aw;  o[2] = tx;
            o[3] = Aw;   o[4] = r00;  o[5] = ty;
            o[6] = 0.0f; o[7] = 0.0f; o[8] = 1.0f;
        }
        __syncthreads();

        // drain: 9*ELEMS floats = 2304 float4, coalesced
        float4* out4 = (float4*)(out + base * 9);
        #pragma unroll
        for (int k = 0; k < 9; ++k)
            out4[t + k * BLOCK] = lds4[t + k * BLOCK];
    } else {
        // ---------- tail path (never hot; n = 2^23 divides evenly) ----------
        for (int j = 0; j < EPT; ++j) {
            long long e = base + t + (long long)j * BLOCK;
            if (e >= n) break;
            float ux = in[3 * e + 0];
            float uy = in[3 * e + 1];
            float w  = in[3 * e + 2];
            float th2 = w * w;
            float th  = fabsf(w);
            float s, c;
            sincosf(th, &s, &c);
            float A   = s / (th + EPSV);
            float Bc  = (1.0f - c) / (th2 + EPSV);
            float Cc  = (1.0f - A) / (th2 + EPSV);
            float r00 = 1.0f - Bc * th2;
            float Aw  = A * w;
            float v00 = 1.0f - Cc * th2;
            float Bw  = Bc * w;
            float tx  = v00 * ux - Bw * uy;
            float ty  = Bw * ux + v00 * uy;
            float* o = out + 9 * e;
            o[0] = r00;  o[1] = -Aw;  o[2] = tx;
            o[3] = Aw;   o[4] = r00;  o[5] = ty;
            o[6] = 0.0f; o[7] = 0.0f; o[8] = 1.0f;
        }
    }
}

extern "C" void kernel_launch(void* const* d_in, const int* in_sizes, int n_in,
                              void* d_out, int out_size, void* d_ws, size_t ws_size,
                              hipStream_t stream) {
    const float* in = (const float*)d_in[0];
    float* out = (float*)d_out;
    long long n = (long long)in_sizes[0] / 3;   // in_sizes[0] = n*3 flat elements
    long long nblk = (n + ELEMS - 1) / ELEMS;
    lie_se2_kernel<<<(int)nblk, BLOCK, 0, stream>>>(in, out, n);
}

// Round 3
// 68.076 us; speedup vs baseline: 1.1726x; 1.1726x over previous
//
#include <hip/hip_runtime.h>
#include <math.h>

#define EPSV 1e-5f

typedef float f32x4 __attribute__((ext_vector_type(4)));

constexpr int BLOCK = 256;
constexpr int EPT   = 2;             // elements per thread
constexpr int ELEMS = BLOCK * EPT;   // 512 elements per block

constexpr int IN_F4  = ELEMS * 3 / 4;   // 384 float4 input stage
constexpr int OUT_F4 = ELEMS * 9 / 4;   // 1152 float4 output drain

__global__ __launch_bounds__(BLOCK) void lie_se2_kernel(
    const float* __restrict__ in,   // [n,3]
    float* __restrict__ out,        // [n,3,3]
    long long n)
{
    __shared__ float lds_in [ELEMS * 3];   // 6 KB
    __shared__ float lds_out[ELEMS * 9];   // 18 KB
    const int t = threadIdx.x;
    const long long base = (long long)blockIdx.x * ELEMS;

    if (base + ELEMS <= n) {
        // ---------- stage input: 384 coalesced nontemporal float4 loads ----------
        const f32x4* in4 = (const f32x4*)(in + base * 3);
        f32x4* li4 = (f32x4*)lds_in;
        #pragma unroll
        for (int k = 0; k < 2; ++k) {
            int idx = t + k * BLOCK;
            if (idx < IN_F4)
                li4[idx] = __builtin_nontemporal_load(in4 + idx);
        }
        __syncthreads();

        // ---------- compute: read lds_in, write lds_out (both ~2-way = free) ----------
        #pragma unroll
        for (int j = 0; j < EPT; ++j) {
            int e = t + j * BLOCK;
            float ux = lds_in[3 * e + 0];
            float uy = lds_in[3 * e + 1];
            float w  = lds_in[3 * e + 2];
            float th2 = w * w;
            float th  = fabsf(w);                 // sqrt(w*w)
            float s, c;
            sincosf(th, &s, &c);
            float A   = s / (th + EPSV);
            float Bc  = (1.0f - c) / (th2 + EPSV);
            float Cc  = (1.0f - A) / (th2 + EPSV);
            float r00 = 1.0f - Bc * th2;
            float Aw  = A * w;
            float v00 = 1.0f - Cc * th2;
            float Bw  = Bc * w;
            float tx  = v00 * ux - Bw * uy;
            float ty  = Bw * ux + v00 * uy;
            float* o = lds_out + 9 * e;
            o[0] = r00;  o[1] = -Aw;  o[2] = tx;
            o[3] = Aw;   o[4] = r00;  o[5] = ty;
            o[6] = 0.0f; o[7] = 0.0f; o[8] = 1.0f;
        }
        __syncthreads();

        // ---------- drain: 1152 coalesced nontemporal float4 stores ----------
        f32x4* out4 = (f32x4*)(out + base * 9);
        const f32x4* lo4 = (const f32x4*)lds_out;
        #pragma unroll
        for (int k = 0; k < 5; ++k) {
            int idx = t + k * BLOCK;
            if (idx < OUT_F4)
                __builtin_nontemporal_store(lo4[idx], out4 + idx);
        }
    } else {
        // ---------- tail path (n = 2^23 divides evenly; never hot) ----------
        for (int j = 0; j < EPT; ++j) {
            long long e = base + t + (long long)j * BLOCK;
            if (e >= n) break;
            float ux = in[3 * e + 0];
            float uy = in[3 * e + 1];
            float w  = in[3 * e + 2];
            float th2 = w * w;
            float th  = fabsf(w);
            float s, c;
            sincosf(th, &s, &c);
            float A   = s / (th + EPSV);
            float Bc  = (1.0f - c) / (th2 + EPSV);
            float Cc  = (1.0f - A) / (th2 + EPSV);
            float r00 = 1.0f - Bc * th2;
            float Aw  = A * w;
            float v00 = 1.0f - Cc * th2;
            float Bw  = Bc * w;
            float tx  = v00 * ux - Bw * uy;
            float ty  = Bw * ux + v00 * uy;
            float* o = out + 9 * e;
            o[0] = r00;  o[1] = -Aw;  o[2] = tx;
            o[3] = Aw;   o[4] = r00;  o[5] = ty;
            o[6] = 0.0f; o[7] = 0.0f; o[8] = 1.0f;
        }
    }
}

extern "C" void kernel_launch(void* const* d_in, const int* in_sizes, int n_in,
                              void* d_out, int out_size, void* d_ws, size_t ws_size,
                              hipStream_t stream) {
    const float* in = (const float*)d_in[0];
    float* out = (float*)d_out;
    long long n = (long long)in_sizes[0] / 3;   // in_sizes[0] = n*3 flat elements
    long long nblk = (n + ELEMS - 1) / ELEMS;
    lie_se2_kernel<<<(int)nblk, BLOCK, 0, stream>>>(in, out, n);
}

// Round 4
// 62.543 us; speedup vs baseline: 1.2763x; 1.0885x over previous
//
#include <hip/hip_runtime.h>
#include <math.h>

#define EPSV 1e-5f

typedef float f32x4 __attribute__((ext_vector_type(4)));

constexpr int BLOCK = 256;
constexpr int EPT   = 2;             // elements per thread
constexpr int ELEMS = BLOCK * EPT;   // 512 elements per block

constexpr int OUT_F4 = ELEMS * 9 / 4;   // 1152 float4 output drain

__global__ __launch_bounds__(BLOCK) void lie_se2_kernel(
    const float* __restrict__ in,   // [n,3]
    float* __restrict__ out,        // [n,3,3]
    long long n)
{
    __shared__ float lds_out[ELEMS * 9];   // 18 KB -> 8 blocks/CU (32 waves, full occupancy)
    const int t = threadIdx.x;
    const long long base = (long long)blockIdx.x * ELEMS;

    if (base + ELEMS <= n) {
        // ---------- compute: direct dwordx3 input load (per-lane 12B contiguous,
        // wave covers a dense 768B region -> fully coalesced), results to LDS ----------
        #pragma unroll
        for (int j = 0; j < EPT; ++j) {
            int e = t + j * BLOCK;
            const float* ip = in + (base + e) * 3;
            float ux = ip[0];
            float uy = ip[1];
            float w  = ip[2];
            float th2 = w * w;
            float th  = fabsf(w);                 // sqrt(w*w)
            float s, c;
            sincosf(th, &s, &c);
            float A   = s / (th + EPSV);
            float Bc  = (1.0f - c) / (th2 + EPSV);
            float Cc  = (1.0f - A) / (th2 + EPSV);
            float r00 = 1.0f - Bc * th2;
            float Aw  = A * w;
            float v00 = 1.0f - Cc * th2;
            float Bw  = Bc * w;
            float tx  = v00 * ux - Bw * uy;
            float ty  = Bw * ux + v00 * uy;
            float* o = lds_out + 9 * e;   // stride-9 = 2-way bank aliasing (free)
            o[0] = r00;  o[1] = -Aw;  o[2] = tx;
            o[3] = Aw;   o[4] = r00;  o[5] = ty;
            o[6] = 0.0f; o[7] = 0.0f; o[8] = 1.0f;
        }
        __syncthreads();

        // ---------- drain: 1152 coalesced nontemporal float4 stores ----------
        f32x4* out4 = (f32x4*)(out + base * 9);
        const f32x4* lo4 = (const f32x4*)lds_out;
        #pragma unroll
        for (int k = 0; k < 5; ++k) {
            int idx = t + k * BLOCK;
            if (idx < OUT_F4)
                __builtin_nontemporal_store(lo4[idx], out4 + idx);
        }
    } else {
        // ---------- tail path (n = 2^23 divides evenly; never hot) ----------
        for (int j = 0; j < EPT; ++j) {
            long long e = base + t + (long long)j * BLOCK;
            if (e >= n) break;
            float ux = in[3 * e + 0];
            float uy = in[3 * e + 1];
            float w  = in[3 * e + 2];
            float th2 = w * w;
            float th  = fabsf(w);
            float s, c;
            sincosf(th, &s, &c);
            float A   = s / (th + EPSV);
            float Bc  = (1.0f - c) / (th2 + EPSV);
            float Cc  = (1.0f - A) / (th2 + EPSV);
            float r00 = 1.0f - Bc * th2;
            float Aw  = A * w;
            float v00 = 1.0f - Cc * th2;
            float Bw  = Bc * w;
            float tx  = v00 * ux - Bw * uy;
            float ty  = Bw * ux + v00 * uy;
            float* o = out + 9 * e;
            o[0] = r00;  o[1] = -Aw;  o[2] = tx;
            o[3] = Aw;   o[4] = r00;  o[5] = ty;
            o[6] = 0.0f; o[7] = 0.0f; o[8] = 1.0f;
        }
    }
}

extern "C" void kernel_launch(void* const* d_in, const int* in_sizes, int n_in,
                              void* d_out, int out_size, void* d_ws, size_t ws_size,
                              hipStream_t stream) {
    const float* in = (const float*)d_in[0];
    float* out = (float*)d_out;
    long long n = (long long)in_sizes[0] / 3;   // in_sizes[0] = n*3 flat elements
    long long nblk = (n + ELEMS - 1) / ELEMS;
    lie_se2_kernel<<<(int)nblk, BLOCK, 0, stream>>>(in, out, n);
}